// Round 1
// baseline (125.372 us; speedup 1.0000x reference)
//
#include <hip/hip_runtime.h>

// out[p] = max(0, segment_max over rows n with idx[n]==p of (feats[n].W + b))
//
// feats: [N][32] fp32, W: [1][32] fp32, b: [1] fp32, idx: [N] int32, out: [P] fp32.
//
// Strategy: memory-bound streaming. Each wave processes 8 rows per step:
// lane l loads float4 #l of the 8-row block (64 consecutive float4 = 1 KiB
// contiguous => perfectly coalesced). 8-lane shuffle tree reduces the dot.
// Segment max via integer atomicMax on positive-float bit patterns
// (out pre-zeroed; negative r can never beat the 0 floor, so skip them).

__global__ __launch_bounds__(256) void miniNN_seglinmax_kernel(
    const float4* __restrict__ feats4,   // N*8 float4
    const float*  __restrict__ W,        // 32 floats
    const float*  __restrict__ b,        // 1 float
    const int*    __restrict__ idx,      // N int32
    int*          __restrict__ out_i,    // P floats viewed as int (pre-zeroed)
    int           n_rows)
{
    const int lane            = threadIdx.x & 63;
    const int sub             = lane & 7;            // which float4 within a row
    const int waves_per_block = blockDim.x >> 6;
    const long long gwid   = (long long)blockIdx.x * waves_per_block + (threadIdx.x >> 6);
    const long long nwaves = (long long)gridDim.x * waves_per_block;

    // Per-lane W fragment (tiny, L2/L1-resident) and bias.
    const float4 wv  = ((const float4*)W)[sub];
    const float bias = b[0];

    const long long ngroups = n_rows >> 3;           // 8 rows per group
    for (long long g = gwid; g < ngroups; g += nwaves) {
        const long long base4 = g << 6;              // first float4 of this group
        const float4 v = feats4[base4 + lane];
        float s = v.x * wv.x + v.y * wv.y + v.z * wv.z + v.w * wv.w;
        // reduce across the 8 lanes that share a row
        s += __shfl_xor(s, 1);
        s += __shfl_xor(s, 2);
        s += __shfl_xor(s, 4);
        if (sub == 0) {
            const long long row = (g << 3) + (lane >> 3);
            const float r = s + bias;
            if (r > 0.0f) {
                // positive floats: int compare == float compare
                atomicMax(&out_i[idx[row]], __float_as_int(r));
            }
        }
    }

    // Tail rows (N % 8 != 0) — scalar path, negligible work.
    const long long tail_start = ngroups << 3;
    const long long gtid = (long long)blockIdx.x * blockDim.x + threadIdx.x;
    const long long row  = tail_start + gtid;
    if (row < n_rows) {
        const float* f = (const float*)feats4 + row * 32;
        float r = bias;
        #pragma unroll
        for (int k = 0; k < 32; ++k) r += f[k] * W[k];
        if (r > 0.0f) {
            atomicMax(&out_i[idx[row]], __float_as_int(r));
        }
    }
}

extern "C" void kernel_launch(void* const* d_in, const int* in_sizes, int n_in,
                              void* d_out, int out_size, void* d_ws, size_t ws_size,
                              hipStream_t stream) {
    const float* feats = (const float*)d_in[0];
    const float* W     = (const float*)d_in[1];
    const float* b     = (const float*)d_in[2];
    const int*   idx   = (const int*)d_in[3];
    const int n_rows   = in_sizes[0] / 32;

    // Zero output: handles empty segments (segment_max -> -inf, then
    // max(.,0) = 0) and is the identity for the positive-float atomicMax.
    hipMemsetAsync(d_out, 0, (size_t)out_size * sizeof(float), stream);

    const int threads = 256;
    const int blocks  = 2048;   // memory-bound: cap grid, grid-stride the rest
    miniNN_seglinmax_kernel<<<blocks, threads, 0, stream>>>(
        (const float4*)feats, W, b, idx, (int*)d_out, n_rows);
}

// Round 2
// 119.215 us; speedup vs baseline: 1.0516x; 1.0516x over previous
//
#include <hip/hip_runtime.h>
#include <limits.h>

// out[p] = max(0, segment_max over rows n with idx[n]==p of (feats[n].W + b))
//
// feats: [N][32] fp32, W: [1][32] fp32, b: [1] fp32, idx: [N] int32, out: [P] fp32.
//
// Memory-bound streaming. Each wave-iteration handles a 32-row "super-group"
// (4 KiB contiguous): 4 independent float4 loads per lane (immediate offsets)
// for MLP=4, then four 8-lane shuffle-tree dot reductions. Segment max via
// integer atomicMax on positive-float bit patterns (out pre-zeroed; r <= 0
// can never beat the 0 floor, so skip those atomics).

__global__ __launch_bounds__(256) void miniNN_seglinmax_kernel(
    const float4* __restrict__ feats4,   // N*8 float4
    const float*  __restrict__ W,        // 32 floats
    const float*  __restrict__ b,        // 1 float
    const int*    __restrict__ idx,      // N int32
    int*          __restrict__ out_i,    // P floats viewed as int (pre-zeroed)
    int           n_rows)
{
    const int lane = threadIdx.x & 63;
    const int sub  = lane & 7;           // which float4 within a row
    const int j    = lane >> 3;          // which row within an 8-row group
    const int gwid = blockIdx.x * (blockDim.x >> 6) + (threadIdx.x >> 6);
    const int nw   = gridDim.x * (blockDim.x >> 6);

    const float4 wv  = ((const float4*)W)[sub];
    const float bias = b[0];

    const int nsuper = n_rows >> 5;      // 32 rows per super-group
    for (int sg = gwid; sg < nsuper; sg += nw) {
        // 4 KiB contiguous per wave-iteration; 4 loads in flight per lane.
        const float4* p = feats4 + (sg << 8) + lane;   // max offset 512MB, int ok
        const float4 v0 = p[0];
        const float4 v1 = p[64];
        const float4 v2 = p[128];
        const float4 v3 = p[192];

        float s0 = v0.x * wv.x + v0.y * wv.y + v0.z * wv.z + v0.w * wv.w;
        float s1 = v1.x * wv.x + v1.y * wv.y + v1.z * wv.z + v1.w * wv.w;
        float s2 = v2.x * wv.x + v2.y * wv.y + v2.z * wv.z + v2.w * wv.w;
        float s3 = v3.x * wv.x + v3.y * wv.y + v3.z * wv.z + v3.w * wv.w;

        s0 += __shfl_xor(s0, 1); s0 += __shfl_xor(s0, 2); s0 += __shfl_xor(s0, 4);
        s1 += __shfl_xor(s1, 1); s1 += __shfl_xor(s1, 2); s1 += __shfl_xor(s1, 4);
        s2 += __shfl_xor(s2, 1); s2 += __shfl_xor(s2, 2); s2 += __shfl_xor(s2, 4);
        s3 += __shfl_xor(s3, 1); s3 += __shfl_xor(s3, 2); s3 += __shfl_xor(s3, 4);

        if (sub == 0) {
            const int rowbase = (sg << 5) + j;
            const int i0 = idx[rowbase];
            const int i1 = idx[rowbase + 8];
            const int i2 = idx[rowbase + 16];
            const int i3 = idx[rowbase + 24];
            const float r0 = s0 + bias;
            const float r1 = s1 + bias;
            const float r2 = s2 + bias;
            const float r3 = s3 + bias;
            if (r0 > 0.0f) atomicMax(out_i + i0, __float_as_int(r0));
            if (r1 > 0.0f) atomicMax(out_i + i1, __float_as_int(r1));
            if (r2 > 0.0f) atomicMax(out_i + i2, __float_as_int(r2));
            if (r3 > 0.0f) atomicMax(out_i + i3, __float_as_int(r3));
        }
    }

    // Tail rows (n_rows % 32 != 0) — scalar path, negligible work.
    const int tail_start = nsuper << 5;
    const int gtid = blockIdx.x * blockDim.x + threadIdx.x;
    const int row  = tail_start + gtid;
    if (row < n_rows) {
        const float* f = (const float*)feats4 + (long long)row * 32;
        float r = bias;
        #pragma unroll
        for (int k = 0; k < 32; ++k) r += f[k] * W[k];
        if (r > 0.0f) atomicMax(out_i + idx[row], __float_as_int(r));
    }
}

extern "C" void kernel_launch(void* const* d_in, const int* in_sizes, int n_in,
                              void* d_out, int out_size, void* d_ws, size_t ws_size,
                              hipStream_t stream) {
    const float* feats = (const float*)d_in[0];
    const float* W     = (const float*)d_in[1];
    const float* b     = (const float*)d_in[2];
    const int*   idx   = (const int*)d_in[3];
    const int n_rows   = in_sizes[0] / 32;

    // Zero output: handles empty segments (segment_max -> -inf, then
    // max(.,0) = 0) and is the identity for the positive-float atomicMax.
    hipMemsetAsync(d_out, 0, (size_t)out_size * sizeof(float), stream);

    // Pick a grid that minimizes grid-stride waste on the super-group loop:
    // waves = blocks*4; minimize ceil(nsuper/waves)*waves - nsuper.
    const int nsuper = n_rows >> 5;
    int best_blocks = 2048;
    long best_waste = LONG_MAX;
    for (int blk = 1024; blk <= 4096; ++blk) {
        const long waves = (long)blk * 4;
        const long iters = (nsuper + waves - 1) / waves;
        const long waste = iters * waves - nsuper;
        if (waste < best_waste) { best_waste = waste; best_blocks = blk; }
    }

    miniNN_seglinmax_kernel<<<best_blocks, 256, 0, stream>>>(
        (const float4*)feats, W, b, idx, (int*)d_out, n_rows);
}

// Round 4
// 114.455 us; speedup vs baseline: 1.0954x; 1.0416x over previous
//
#include <hip/hip_runtime.h>

// out[p] = max(0, segment_max over rows n with idx[n]==p of (feats[n].W + b))
//
// feats: [N][32] fp32, W: [1][32] fp32, b: [1] fp32, idx: [N] int32, out: [P] fp32.
//
// Memory-bound streaming, SINGLE dispatch round (blocks <= 2048 resident
// capacity at 8 blocks/CU, enforced via __launch_bounds__(256,8)):
// each wave-iteration handles a 32-row super-group (4 KiB contiguous),
// 4 independent nontemporal float4 loads per lane (MLP=4), 8-lane shuffle
// tree per row-dot. Segment max via integer atomicMax on positive-float
// bit patterns (out pre-zeroed; r <= 0 never beats the 0 floor).

// Native clang vector type: __builtin_nontemporal_load requires a pointer to
// scalar/vector-of-scalar, NOT HIP's struct-based float4.
typedef float f32x4 __attribute__((ext_vector_type(4)));

__global__ __launch_bounds__(256, 8) void miniNN_seglinmax_kernel(
    const f32x4* __restrict__ feats4,    // N*8 float4
    const float* __restrict__ W,         // 32 floats
    const float* __restrict__ b,         // 1 float
    const int*   __restrict__ idx,       // N int32
    int*         __restrict__ out_i,     // P floats viewed as int (pre-zeroed)
    int          n_rows)
{
    const int lane = threadIdx.x & 63;
    const int sub  = lane & 7;           // which float4 within a row
    const int j    = lane >> 3;          // which row within an 8-row group
    const int gwid = blockIdx.x * (blockDim.x >> 6) + (threadIdx.x >> 6);
    const int nw   = gridDim.x * (blockDim.x >> 6);

    const f32x4 wv  = ((const f32x4*)W)[sub];
    const float bias = b[0];

    const int nsuper = n_rows >> 5;      // 32 rows per super-group
    for (int sg = gwid; sg < nsuper; sg += nw) {
        // 4 KiB contiguous per wave-iteration; 4 loads in flight per lane.
        // Nontemporal: feats is streamed exactly once — keep out/W in cache.
        const f32x4* p = feats4 + (sg << 8) + lane;
        const f32x4 v0 = __builtin_nontemporal_load(p);
        const f32x4 v1 = __builtin_nontemporal_load(p + 64);
        const f32x4 v2 = __builtin_nontemporal_load(p + 128);
        const f32x4 v3 = __builtin_nontemporal_load(p + 192);

        float s0 = v0.x * wv.x + v0.y * wv.y + v0.z * wv.z + v0.w * wv.w;
        float s1 = v1.x * wv.x + v1.y * wv.y + v1.z * wv.z + v1.w * wv.w;
        float s2 = v2.x * wv.x + v2.y * wv.y + v2.z * wv.z + v2.w * wv.w;
        float s3 = v3.x * wv.x + v3.y * wv.y + v3.z * wv.z + v3.w * wv.w;

        s0 += __shfl_xor(s0, 1); s0 += __shfl_xor(s0, 2); s0 += __shfl_xor(s0, 4);
        s1 += __shfl_xor(s1, 1); s1 += __shfl_xor(s1, 2); s1 += __shfl_xor(s1, 4);
        s2 += __shfl_xor(s2, 1); s2 += __shfl_xor(s2, 2); s2 += __shfl_xor(s2, 4);
        s3 += __shfl_xor(s3, 1); s3 += __shfl_xor(s3, 2); s3 += __shfl_xor(s3, 4);

        if (sub == 0) {
            const int rowbase = (sg << 5) + j;
            const int i0 = __builtin_nontemporal_load(idx + rowbase);
            const int i1 = __builtin_nontemporal_load(idx + rowbase + 8);
            const int i2 = __builtin_nontemporal_load(idx + rowbase + 16);
            const int i3 = __builtin_nontemporal_load(idx + rowbase + 24);
            const float r0 = s0 + bias;
            const float r1 = s1 + bias;
            const float r2 = s2 + bias;
            const float r3 = s3 + bias;
            if (r0 > 0.0f) atomicMax(out_i + i0, __float_as_int(r0));
            if (r1 > 0.0f) atomicMax(out_i + i1, __float_as_int(r1));
            if (r2 > 0.0f) atomicMax(out_i + i2, __float_as_int(r2));
            if (r3 > 0.0f) atomicMax(out_i + i3, __float_as_int(r3));
        }
    }

    // Tail rows (n_rows % 32 != 0) — scalar path, negligible work.
    const int tail_start = nsuper << 5;
    const int gtid = blockIdx.x * blockDim.x + threadIdx.x;
    const int row  = tail_start + gtid;
    if (row < n_rows) {
        const float* f = (const float*)feats4 + (long long)row * 32;
        float r = bias;
        #pragma unroll
        for (int k = 0; k < 32; ++k) r += f[k] * W[k];
        if (r > 0.0f) atomicMax(out_i + idx[row], __float_as_int(r));
    }
}

extern "C" void kernel_launch(void* const* d_in, const int* in_sizes, int n_in,
                              void* d_out, int out_size, void* d_ws, size_t ws_size,
                              hipStream_t stream) {
    const float* feats = (const float*)d_in[0];
    const float* W     = (const float*)d_in[1];
    const float* b     = (const float*)d_in[2];
    const int*   idx   = (const int*)d_in[3];
    const int n_rows   = in_sizes[0] / 32;

    // Zero output: handles empty segments (segment_max -> -inf, then
    // max(.,0) = 0) and is the identity for the positive-float atomicMax.
    (void)hipMemsetAsync(d_out, 0, (size_t)out_size * sizeof(float), stream);

    // SINGLE-ROUND grid: capacity = 256 CU x 8 blocks/CU = 2048 resident
    // blocks (4-wave blocks, VGPR<=64 via launch_bounds). Choose blocks
    // <= 2048 minimizing total wave-iteration slots (waves * iters), i.e.
    // one uniform round with near-perfect balance. For nsuper=125000 this
    // picks 1954 blocks: 7816 waves x 16 iters = 125056 (99.96% util).
    const int nsuper = n_rows >> 5;
    int best_blocks = 2048;
    long long best_cost = 0x7fffffffffffffffLL;
    for (int blk = 256; blk <= 2048; ++blk) {
        const long long waves = (long long)blk * 4;
        const long long iters = (nsuper + waves - 1) / waves;
        const long long cost  = waves * iters;
        if (cost < best_cost || (cost == best_cost && blk > best_blocks)) {
            best_cost = cost; best_blocks = blk;
        }
    }

    miniNN_seglinmax_kernel<<<best_blocks, 256, 0, stream>>>(
        (const f32x4*)feats, W, b, idx, (int*)d_out, n_rows);
}